// Round 16
// baseline (863.557 us; speedup 1.0000x reference)
//
#include <hip/hip_runtime.h>

#define N_NODES 100000
#define N_EDGES 500000
#define NODE_IN 16
#define HID 128
#define LPAD 140          // LDS row stride (floats)
#define SCAN_CHUNK 1024
#define NB_SCAN ((N_NODES + SCAN_CHUNK - 1) / SCAN_CHUNK)   // 98
#define DBINS 1024
#define NBLK64 1563       // ceil(N_NODES/64)
#define PERM_PAD (NBLK64 * 64)   // 100032

typedef __attribute__((ext_vector_type(8))) short short8;   // 8×16b in 4 VGPRs
typedef __attribute__((ext_vector_type(4))) float f32x4;    // MFMA accumulator

__device__ __forceinline__ float elu_f(float v) {
    return v > 0.f ? v : __expf(v) - 1.f;
}

// bf16 pack/unpack (rne)
__device__ __forceinline__ unsigned short f2b(float f) {
    unsigned int u = __float_as_uint(f);
    unsigned int r = (u + 0x7fffu + ((u >> 16) & 1u)) >> 16;
    return (unsigned short)r;
}
__device__ __forceinline__ float b2f(unsigned short h) {
    return __uint_as_float((unsigned int)h << 16);
}
// fp16 pack/unpack
__device__ __forceinline__ unsigned short f2h(float f) {
    _Float16 h = (_Float16)f;
    unsigned short u;
    __builtin_memcpy(&u, &h, 2);
    return u;
}
__device__ __forceinline__ float h2f(unsigned short u) {
    _Float16 h;
    __builtin_memcpy(&h, &u, 2);
    return (float)h;
}

// ===========================================================================
// CSR-by-dst build
// ===========================================================================
__global__ void deg_count_kernel(const int* __restrict__ ei, int* __restrict__ deg) {
    int e = blockIdx.x * 256 + threadIdx.x;
    if (e < N_EDGES) atomicAdd(&deg[ei[N_EDGES + e]], 1);
}

__global__ __launch_bounds__(1024) void scanA_kernel(const int* __restrict__ deg, int* __restrict__ bsum) {
    __shared__ int s[SCAN_CHUNK];
    int i = blockIdx.x * SCAN_CHUNK + threadIdx.x;
    s[threadIdx.x] = (i < N_NODES) ? deg[i] : 0;
    __syncthreads();
    for (int off = SCAN_CHUNK / 2; off > 0; off >>= 1) {
        if (threadIdx.x < off) s[threadIdx.x] += s[threadIdx.x + off];
        __syncthreads();
    }
    if (threadIdx.x == 0) bsum[blockIdx.x] = s[0];
}

__global__ void scanB_kernel(const int* __restrict__ bsum, int* __restrict__ boff,
                             int* __restrict__ rowPtr) {
    if (threadIdx.x == 0 && blockIdx.x == 0) {
        int r = 0;
        for (int i = 0; i < NB_SCAN; i++) { boff[i] = r; r += bsum[i]; }
        rowPtr[N_NODES] = N_EDGES;
    }
}

__global__ __launch_bounds__(1024) void scanC_kernel(const int* __restrict__ deg,
                                                     const int* __restrict__ boff,
                                                     int* __restrict__ rowPtr,
                                                     int* __restrict__ cursor) {
    __shared__ int bufA[SCAN_CHUNK], bufB[SCAN_CHUNK];
    int i = blockIdx.x * SCAN_CHUNK + threadIdx.x;
    int t = threadIdx.x;
    bufA[t] = (i < N_NODES) ? deg[i] : 0;
    __syncthreads();
    int* src = bufA; int* dst = bufB;
    for (int off = 1; off < SCAN_CHUNK; off <<= 1) {
        dst[t] = (t >= off) ? (src[t - off] + src[t]) : src[t];
        __syncthreads();
        int* tmp = src; src = dst; dst = tmp;
    }
    if (i < N_NODES) {
        int excl = (t == 0) ? 0 : src[t - 1];
        int v = excl + boff[blockIdx.x];
        rowPtr[i] = v;
        cursor[i] = v;
    }
}

// payload reorder: (src, ea) packed int2 in CSR(dst) order
__global__ void fill_kernel(const int* __restrict__ ei, const float* __restrict__ ea,
                            int* __restrict__ cursor, int2* __restrict__ edgeP) {
    int e = blockIdx.x * 256 + threadIdx.x;
    if (e < N_EDGES) {
        int d = ei[N_EDGES + e];
        int p = atomicAdd(&cursor[d], 1);
        edgeP[p] = make_int2(ei[e], __float_as_int(ea[e]));
    }
}

// ===========================================================================
// Degree counting sort, contention-free, parallel scan
// ===========================================================================
__global__ __launch_bounds__(1024) void s1_blockhist_kernel(const int* __restrict__ deg,
                                                            int* __restrict__ blockHist) {
    __shared__ int h[DBINS];
    int t = threadIdx.x, b = blockIdx.x;
    h[t] = 0;
    __syncthreads();
    int i = b * SCAN_CHUNK + t;
    if (i < N_NODES) atomicAdd(&h[min(deg[i], DBINS - 1)], 1);
    __syncthreads();
    blockHist[b * DBINS + t] = h[t];
}

// s2a: per-bin column exclusive prefix over the 98 blocks (1024 indep columns)
__global__ __launch_bounds__(256) void s2a_colscan_kernel(int* __restrict__ blockHist,
                                                          int* __restrict__ binTot) {
    int k = blockIdx.x * 256 + threadIdx.x;
    if (k >= DBINS) return;
    int r = 0;
#pragma unroll 7
    for (int b = 0; b < NB_SCAN; b++) {
        int v = blockHist[b * DBINS + k];
        blockHist[b * DBINS + k] = r;
        r += v;
    }
    binTot[k] = r;
}

// s2b: exclusive scan of 1024 bin totals (single block, LDS)
__global__ __launch_bounds__(1024) void s2b_binscan_kernel(const int* __restrict__ binTot,
                                                           int* __restrict__ binStart) {
    __shared__ int bufA[DBINS], bufB[DBINS];
    int k = threadIdx.x;
    bufA[k] = binTot[k];
    __syncthreads();
    int* src = bufA; int* dst = bufB;
    for (int off = 1; off < DBINS; off <<= 1) {
        dst[k] = (k >= off) ? (src[k - off] + src[k]) : src[k];
        __syncthreads();
        int* tmp = src; src = dst; dst = tmp;
    }
    binStart[k] = (k == 0) ? 0 : src[k - 1];
}

// s3: scatter via LDS cursors (binStart fused in)
__global__ __launch_bounds__(1024) void s3_scatter_kernel(const int* __restrict__ deg,
                                                          const int* __restrict__ blockHist,
                                                          const int* __restrict__ binStart,
                                                          int* __restrict__ perm) {
    __shared__ int cur[DBINS];
    int t = threadIdx.x, b = blockIdx.x;
    cur[t] = blockHist[b * DBINS + t] + binStart[t];
    __syncthreads();
    int i = b * SCAN_CHUNK + t;
    if (i < N_NODES) {
        int k = min(deg[i], DBINS - 1);
        int p = atomicAdd(&cur[k], 1);            // LDS atomic, intra-block only
        perm[p] = i;
    }
}

// ===========================================================================
// Merged weight pack: all 10 matrices in one dispatch.
// slots: [0..3]=W1 hi, [4..7]=W1 lo, [8..11]=W2 hi, [12..15]=W2 lo,
//        [16,17]=Wp1 top hi/lo, [18,19]=Wp1 bot hi/lo
// ===========================================================================
__global__ __launch_bounds__(256) void pack_all_kernel(
    const float* __restrict__ W1_s, const float* __restrict__ W2_s,
    const float* __restrict__ Wp1, unsigned short* __restrict__ wpk)
{
    int gid = blockIdx.x * 256 + threadIdx.x;   // 10 * 2048
    if (gid >= 10 * 2048) return;
    int m = gid >> 11, r = gid & 2047;
    const float* W; int K_off = 0; int hi_slot, lo_slot;
    if (m < 4)       { W = W1_s + (size_t)m * 16384;       hi_slot = m;          lo_slot = 4 + m; }
    else if (m < 8)  { W = W2_s + (size_t)(m - 4) * 16384; hi_slot = 8 + (m - 4); lo_slot = 12 + (m - 4); }
    else if (m == 8) { W = Wp1; K_off = 0;   hi_slot = 16; lo_slot = 17; }
    else             { W = Wp1; K_off = 128; hi_slot = 18; lo_slot = 19; }
    int lane = r & 63, tl = (r >> 6) & 7, ch = r >> 9;
    int kb = ch * 32 + (lane >> 4) * 8;
    int n  = tl * 16 + (lane & 15);
    unsigned short* hi = wpk + (size_t)hi_slot * 16384;
    unsigned short* lo = wpk + (size_t)lo_slot * 16384;
    for (int j = 0; j < 8; j++) {
        float w = W[(size_t)(K_off + kb + j) * 128 + n];
        unsigned short h = f2b(w);
        hi[(size_t)r * 8 + j] = h;
        lo[(size_t)r * 8 + j] = f2b(w - b2f(h));
    }
}

// ===========================================================================
// Layer 0 scatter (fp32 aggr, NODE_IN=16)
// ===========================================================================
__global__ __launch_bounds__(256) void scatter0_kernel(
    const float* __restrict__ x, const int* __restrict__ ei,
    const float* __restrict__ ea, const float* __restrict__ We0,
    const float* __restrict__ be0, float* __restrict__ aggr)
{
    int idx = blockIdx.x * 256 + threadIdx.x;
    int e = idx >> 4, c = idx & 15;
    int s = ei[e], d = ei[N_EDGES + e];
    float m = x[s * NODE_IN + c] + ea[e] * We0[c] + be0[c];
    m = fmaxf(m, 0.f);
    atomicAdd(&aggr[d * NODE_IN + c], m);
}

// ---------------------------------------------------------------------------
__device__ __forceinline__ void fma4x4(float (&acc)[4][4],
    const float4& r0, const float4& r1, const float4& r2, const float4& r3,
    const float4& w0, const float4& w1, const float4& w2, const float4& w3)
{
    float r[4][4] = {{r0.x, r0.y, r0.z, r0.w}, {r1.x, r1.y, r1.z, r1.w},
                     {r2.x, r2.y, r2.z, r2.w}, {r3.x, r3.y, r3.z, r3.w}};
    float w[4][4] = {{w0.x, w0.y, w0.z, w0.w}, {w1.x, w1.y, w1.z, w1.w},
                     {w2.x, w2.y, w2.z, w2.w}, {w3.x, w3.y, w3.z, w3.w}};
#pragma unroll
    for (int i = 0; i < 4; i++)
#pragma unroll
        for (int k = 0; k < 4; k++)
#pragma unroll
            for (int c = 0; c < 4; c++)
                acc[i][c] = fmaf(r[i][k], w[k][c], acc[i][c]);
}

// ===========================================================================
// Layer 0 MLP (fp32 vector) -> writes h as fp16
// ===========================================================================
__global__ __launch_bounds__(256) void mlp0_kernel(
    const float* __restrict__ x, const float* __restrict__ aggr,
    const float* __restrict__ W1, const float* __restrict__ b1,
    const float* __restrict__ W2, const float* __restrict__ b2,
    unsigned short* __restrict__ h)
{
    __shared__ float in0[32][20];
    __shared__ float mid[32][HID];
    const int t = threadIdx.x;
    const int q = t & 31, g = t >> 5;
    const int c0 = q * 4;
    const int base = blockIdx.x * 32;

    for (int i = t; i < 32 * NODE_IN; i += 256) {
        int r = i >> 4, cc = i & 15;
        int n = base + r;
        in0[r][cc] = x[n * NODE_IN + cc] + aggr[n * NODE_IN + cc];
    }
    __syncthreads();

    float4 bb = *(const float4*)&b1[c0];
    float acc[4][4];
#pragma unroll
    for (int i = 0; i < 4; i++) { acc[i][0] = bb.x; acc[i][1] = bb.y; acc[i][2] = bb.z; acc[i][3] = bb.w; }
    for (int k = 0; k < NODE_IN; k += 4) {
        float4 r0 = *(const float4*)&in0[g * 4 + 0][k];
        float4 r1 = *(const float4*)&in0[g * 4 + 1][k];
        float4 r2 = *(const float4*)&in0[g * 4 + 2][k];
        float4 r3 = *(const float4*)&in0[g * 4 + 3][k];
        float4 w0 = *(const float4*)&W1[(k + 0) * HID + c0];
        float4 w1 = *(const float4*)&W1[(k + 1) * HID + c0];
        float4 w2 = *(const float4*)&W1[(k + 2) * HID + c0];
        float4 w3 = *(const float4*)&W1[(k + 3) * HID + c0];
        fma4x4(acc, r0, r1, r2, r3, w0, w1, w2, w3);
    }
#pragma unroll
    for (int i = 0; i < 4; i++)
        *(float4*)&mid[g * 4 + i][c0] = make_float4(elu_f(acc[i][0]), elu_f(acc[i][1]),
                                                    elu_f(acc[i][2]), elu_f(acc[i][3]));
    __syncthreads();

    float4 bb2 = *(const float4*)&b2[c0];
    float acc2[4][4];
#pragma unroll
    for (int i = 0; i < 4; i++) { acc2[i][0] = bb2.x; acc2[i][1] = bb2.y; acc2[i][2] = bb2.z; acc2[i][3] = bb2.w; }
    for (int k = 0; k < HID; k += 4) {
        float4 r0 = *(const float4*)&mid[g * 4 + 0][k];
        float4 r1 = *(const float4*)&mid[g * 4 + 1][k];
        float4 r2 = *(const float4*)&mid[g * 4 + 2][k];
        float4 r3 = *(const float4*)&mid[g * 4 + 3][k];
        float4 w0 = *(const float4*)&W2[(k + 0) * HID + c0];
        float4 w1 = *(const float4*)&W2[(k + 1) * HID + c0];
        float4 w2 = *(const float4*)&W2[(k + 2) * HID + c0];
        float4 w3 = *(const float4*)&W2[(k + 3) * HID + c0];
        fma4x4(acc2, r0, r1, r2, r3, w0, w1, w2, w3);
    }
#pragma unroll
    for (int i = 0; i < 4; i++) {
        ushort4 o;
        o.x = f2h(elu_f(acc2[i][0])); o.y = f2h(elu_f(acc2[i][1]));
        o.z = f2h(elu_f(acc2[i][2])); o.w = f2h(elu_f(acc2[i][3]));
        *(ushort4*)&h[(size_t)(base + g * 4 + i) * HID + c0] = o;
    }
}

// ---------------------------------------------------------------------------
// A-fragment load+split from LDS (fp32 -> hi/lo bf16), layout per m120
// ---------------------------------------------------------------------------
__device__ __forceinline__ void afrag_split(const float (&buf)[16][LPAD], int lane,
                                            short8 (&ah)[4], short8 (&al)[4])
{
    const int m = lane & 15, s8 = (lane >> 4) * 8;
#pragma unroll
    for (int ch = 0; ch < 4; ch++) {
        float4 a0 = *(const float4*)&buf[m][ch * 32 + s8];
        float4 a1 = *(const float4*)&buf[m][ch * 32 + s8 + 4];
        float av[8] = {a0.x, a0.y, a0.z, a0.w, a1.x, a1.y, a1.z, a1.w};
#pragma unroll
        for (int j = 0; j < 8; j++) {
            unsigned short h = f2b(av[j]);
            ah[ch][j] = (short)h;
            al[ch][j] = (short)f2b(av[j] - b2f(h));
        }
    }
}

// ===========================================================================
// Fused GINE HID layer, v13: 16-SLOT gather pipeline (4 steps x 4 rows in
// flight, next-batch indices prefetched) — probes the concurrency-vs-BW wall.
// 4 waves/block x 16 sorted nodes; fp16 h storage; split-bf16 MFMA MLP.
// ===========================================================================
template <bool PRED>
__global__ __launch_bounds__(256, 4) void gine_mfma_kernel(
    const unsigned short* __restrict__ hin, const int* __restrict__ rowPtr,
    const int2* __restrict__ edgeP, const int* __restrict__ perm,
    const float* __restrict__ We, const float* __restrict__ be,
    const unsigned short* __restrict__ W1h, const unsigned short* __restrict__ W1l,
    const float* __restrict__ b1,
    const unsigned short* __restrict__ W2h, const unsigned short* __restrict__ W2l,
    const float* __restrict__ b2,
    unsigned short* __restrict__ hout,
    const unsigned short* __restrict__ P1h, const unsigned short* __restrict__ P1l,
    const unsigned short* __restrict__ P2h, const unsigned short* __restrict__ P2l,
    unsigned short* __restrict__ Pbuf)
{
    __shared__ float bufAll[4][16][LPAD];   // 35.84 KB, one slice per wave
    const int w = threadIdx.x >> 6;
    const int lane = threadIdx.x & 63;
    float (&buf)[16][LPAD] = bufAll[w];
    const int qg = lane & 15, rg = lane >> 4;
    const int c0 = qg * 8;                  // 16 lanes x 8 cols
    const int base = blockIdx.x * 64 + w * 16;

    float wev[8], bev[8];
#pragma unroll
    for (int j = 0; j < 8; j++) { wev[j] = We[c0 + j]; bev[j] = be[c0 + j]; }

    // ---- stage 1: 16-slot pipelined gather over degree-sorted nodes ----
    int nn[4], s0[4], e0[4];
    float acc[4][8];
#pragma unroll
    for (int i = 0; i < 4; i++) {
        nn[i] = perm[base + rg * 4 + i];
        s0[i] = rowPtr[nn[i]];
        e0[i] = rowPtr[nn[i] + 1];
        short8 h0 = *(const short8*)&hin[(size_t)nn[i] * HID + c0];
#pragma unroll
        for (int j = 0; j < 8; j++) acc[i][j] = h2f((unsigned short)h0[j]);
    }
    int maxd = 0;
#pragma unroll
    for (int i = 0; i < 4; i++) maxd = max(maxd, e0[i] - s0[i]);

    int idx[16]; float av[16]; bool act[16];
#pragma unroll
    for (int u = 0; u < 4; u++)
#pragma unroll
        for (int i = 0; i < 4; i++) {
            int slot = u * 4 + i;
            int j = s0[i] + u;
            act[slot] = j < e0[i];
            int jc = act[slot] ? j : (N_EDGES - 1);
            int2 ep = edgeP[jc];
            idx[slot] = ep.x;
            av[slot]  = __int_as_float(ep.y);
        }

    for (int sb = 0; sb < maxd; sb += 4) {
        short8 hraw[16];
#pragma unroll
        for (int s = 0; s < 16; s++)
            hraw[s] = *(const short8*)&hin[(size_t)idx[s] * HID + c0];

        int nidx[16]; float nav[16]; bool nact[16];
#pragma unroll
        for (int u = 0; u < 4; u++)
#pragma unroll
            for (int i = 0; i < 4; i++) {
                int slot = u * 4 + i;
                int j = s0[i] + sb + 4 + u;
                nact[slot] = j < e0[i];
                int jc = nact[slot] ? j : (N_EDGES - 1);
                int2 ep = edgeP[jc];
                nidx[slot] = ep.x;
                nav[slot]  = __int_as_float(ep.y);
            }

#pragma unroll
        for (int u = 0; u < 4; u++)
#pragma unroll
            for (int i = 0; i < 4; i++) {
                int slot = u * 4 + i;
                if (act[slot]) {
#pragma unroll
                    for (int j = 0; j < 8; j++) {
                        float hv = h2f((unsigned short)hraw[slot][j]);
                        acc[i][j] += fmaxf(fmaf(av[slot], wev[j], bev[j]) + hv, 0.f);
                    }
                }
            }
#pragma unroll
        for (int s = 0; s < 16; s++) {
            idx[s] = nidx[s]; av[s] = nav[s]; act[s] = nact[s];
        }
    }
#pragma unroll
    for (int i = 0; i < 4; i++) {
        *(float4*)&buf[rg * 4 + i][c0]     = make_float4(acc[i][0], acc[i][1], acc[i][2], acc[i][3]);
        *(float4*)&buf[rg * 4 + i][c0 + 4] = make_float4(acc[i][4], acc[i][5], acc[i][6], acc[i][7]);
    }
    __syncthreads();   // waves have equal degree (sorted) -> negligible convoy

    const int col16 = lane & 15, r0 = (lane >> 4) * 4;

    // ---- stage 2: mid = elu(in @ W1 + b1), split-bf16 MFMA, in-place ----
    {
        short8 ah[4], al[4];
        afrag_split(buf, lane, ah, al);
        float res[8][4];
#pragma unroll
        for (int tl = 0; tl < 8; tl++) {
            int col = tl * 16 + col16;
            float bv = b1[col];
            f32x4 c = {bv, bv, bv, bv};
#pragma unroll
            for (int ch = 0; ch < 4; ch++) {
                int off = ((ch * 8 + tl) * 64 + lane) * 8;
                short8 bh = *(const short8*)&W1h[off];
                short8 bl = *(const short8*)&W1l[off];
                c = __builtin_amdgcn_mfma_f32_16x16x32_bf16(ah[ch], bh, c, 0, 0, 0);
                c = __builtin_amdgcn_mfma_f32_16x16x32_bf16(al[ch], bh, c, 0, 0, 0);
                c = __builtin_amdgcn_mfma_f32_16x16x32_bf16(ah[ch], bl, c, 0, 0, 0);
            }
#pragma unroll
            for (int r = 0; r < 4; r++) res[tl][r] = elu_f(c[r]);
        }
        __syncthreads();
#pragma unroll
        for (int tl = 0; tl < 8; tl++)
#pragma unroll
            for (int r = 0; r < 4; r++)
                buf[r0 + r][tl * 16 + col16] = res[tl][r];
    }
    __syncthreads();

    // ---- stage 3: h = elu(mid @ W2 + b2), in-place ----
    {
        short8 ah[4], al[4];
        afrag_split(buf, lane, ah, al);
        float res[8][4];
#pragma unroll
        for (int tl = 0; tl < 8; tl++) {
            int col = tl * 16 + col16;
            float bv = b2[col];
            f32x4 c = {bv, bv, bv, bv};
#pragma unroll
            for (int ch = 0; ch < 4; ch++) {
                int off = ((ch * 8 + tl) * 64 + lane) * 8;
                short8 bh = *(const short8*)&W2h[off];
                short8 bl = *(const short8*)&W2l[off];
                c = __builtin_amdgcn_mfma_f32_16x16x32_bf16(ah[ch], bh, c, 0, 0, 0);
                c = __builtin_amdgcn_mfma_f32_16x16x32_bf16(al[ch], bh, c, 0, 0, 0);
                c = __builtin_amdgcn_mfma_f32_16x16x32_bf16(ah[ch], bl, c, 0, 0, 0);
            }
#pragma unroll
            for (int r = 0; r < 4; r++) res[tl][r] = elu_f(c[r]);
        }
        __syncthreads();
#pragma unroll
        for (int tl = 0; tl < 8; tl++)
#pragma unroll
            for (int r = 0; r < 4; r++)
                buf[r0 + r][tl * 16 + col16] = res[tl][r];
    }
    __syncthreads();

    if constexpr (!PRED) {
        // fp16 store of h (row-scattered by perm; 256 B contiguous per row)
#pragma unroll
        for (int i = 0; i < 4; i++) {
            short8 o;
#pragma unroll
            for (int j = 0; j < 8; j++) o[j] = (short)f2h(buf[rg * 4 + i][c0 + j]);
            *(short8*)&hout[(size_t)nn[i] * HID + c0] = o;
        }
    } else {
        // P1|P2 = h @ Wp1 halves, emit bf16 packed rows (perm-indexed)
        short8 ah[4], al[4];
        afrag_split(buf, lane, ah, al);
        int pn[4];
#pragma unroll
        for (int r = 0; r < 4; r++) pn[r] = perm[base + r0 + r];
#pragma unroll
        for (int tl = 0; tl < 8; tl++) {
            int col = tl * 16 + col16;
            f32x4 c1 = {0.f, 0.f, 0.f, 0.f};
            f32x4 c2 = {0.f, 0.f, 0.f, 0.f};
#pragma unroll
            for (int ch = 0; ch < 4; ch++) {
                int off = ((ch * 8 + tl) * 64 + lane) * 8;
                short8 bh1 = *(const short8*)&P1h[off];
                short8 bl1 = *(const short8*)&P1l[off];
                c1 = __builtin_amdgcn_mfma_f32_16x16x32_bf16(ah[ch], bh1, c1, 0, 0, 0);
                c1 = __builtin_amdgcn_mfma_f32_16x16x32_bf16(al[ch], bh1, c1, 0, 0, 0);
                c1 = __builtin_amdgcn_mfma_f32_16x16x32_bf16(ah[ch], bl1, c1, 0, 0, 0);
                short8 bh2 = *(const short8*)&P2h[off];
                short8 bl2 = *(const short8*)&P2l[off];
                c2 = __builtin_amdgcn_mfma_f32_16x16x32_bf16(ah[ch], bh2, c2, 0, 0, 0);
                c2 = __builtin_amdgcn_mfma_f32_16x16x32_bf16(al[ch], bh2, c2, 0, 0, 0);
                c2 = __builtin_amdgcn_mfma_f32_16x16x32_bf16(ah[ch], bl2, c2, 0, 0, 0);
            }
#pragma unroll
            for (int r = 0; r < 4; r++) {
                size_t n = (size_t)pn[r];
                Pbuf[n * 256 + col]       = f2b(c1[r]);
                Pbuf[n * 256 + 128 + col] = f2b(c2[r]);
            }
        }
    }
}

// ===========================================================================
// Edge predictor tail
// ===========================================================================
__global__ __launch_bounds__(256) void pred_edge_kernel(
    const unsigned short* __restrict__ Pbuf, const int* __restrict__ ei,
    const float* __restrict__ bp1, const float* __restrict__ Wp2,
    const float* __restrict__ bp2, float* __restrict__ out)
{
    const int t = threadIdx.x;
    const int lane = t & 31;
    const int eloc = t >> 5;
    const int e = blockIdx.x * 8 + eloc;
    const int c0 = lane * 4;

    int s = ei[e], d = ei[N_EDGES + e];
    ushort4 ua = *(const ushort4*)&Pbuf[(size_t)s * 256 + c0];
    ushort4 ub = *(const ushort4*)&Pbuf[(size_t)d * 256 + 128 + c0];
    float4 bb = *(const float4*)&bp1[c0];
    float4 w = *(const float4*)&Wp2[c0];
    float r = elu_f(b2f(ua.x) + b2f(ub.x) + bb.x) * w.x
            + elu_f(b2f(ua.y) + b2f(ub.y) + bb.y) * w.y
            + elu_f(b2f(ua.z) + b2f(ub.z) + bb.z) * w.z
            + elu_f(b2f(ua.w) + b2f(ub.w) + bb.w) * w.w;
#pragma unroll
    for (int off = 16; off > 0; off >>= 1) r += __shfl_down(r, off, 32);
    if (lane == 0) out[e] = r + bp2[0];
}

// ===========================================================================
extern "C" void kernel_launch(void* const* d_in, const int* in_sizes, int n_in,
                              void* d_out, int out_size, void* d_ws, size_t ws_size,
                              hipStream_t stream) {
    const float* x    = (const float*)d_in[0];
    const int*   ei   = (const int*)d_in[1];
    const float* ea   = (const float*)d_in[2];
    const float* We0  = (const float*)d_in[3];
    const float* be0  = (const float*)d_in[4];
    const float* W10  = (const float*)d_in[5];
    const float* b10  = (const float*)d_in[6];
    const float* W20  = (const float*)d_in[7];
    const float* b20  = (const float*)d_in[8];
    const float* We_s = (const float*)d_in[9];
    const float* be_s = (const float*)d_in[10];
    const float* W1_s = (const float*)d_in[11];
    const float* b1_s = (const float*)d_in[12];
    const float* W2_s = (const float*)d_in[13];
    const float* b2_s = (const float*)d_in[14];
    const float* Wp1  = (const float*)d_in[15];
    const float* bp1  = (const float*)d_in[16];
    const float* Wp2  = (const float*)d_in[17];
    const float* bp2  = (const float*)d_in[18];
    float* out = (float*)d_out;

    // workspace: h16A (25.6MB) | h16B (25.6MB) | Pbuf (51.2MB) | R
    unsigned short* h16A = (unsigned short*)d_ws;
    unsigned short* h16B = h16A + (size_t)N_NODES * HID;
    unsigned short* Pbuf = h16B + (size_t)N_NODES * HID;
    float* R = (float*)(Pbuf + (size_t)N_NODES * 256);

    float* aggr0 = R;                                  // N*16 f32
    int* deg     = (int*)(aggr0 + (size_t)N_NODES * NODE_IN);
    int* rowPtr  = deg + N_NODES;                      // N+1 ints
    int* cursor  = rowPtr + N_NODES + 1;
    int2* edgeP  = (int2*)(cursor + N_NODES);          // 500k int2
    int* bsum    = (int*)(edgeP + N_EDGES);
    int* boff    = bsum + NB_SCAN;
    int* perm    = boff + NB_SCAN;                     // PERM_PAD ints
    int* blockHist = perm + PERM_PAD;                  // 98*1024
    int* binTot   = blockHist + NB_SCAN * DBINS;       // 1024
    int* binStart = binTot + DBINS;                    // 1024

    // packed weights: 20 slots x 16384 ushorts = 640 KB, at R+24MB
    unsigned short* wpk = (unsigned short*)(R + (size_t)6 * 1024 * 1024);

    // ----- CSR build -----
    hipMemsetAsync(deg, 0, N_NODES * sizeof(int), stream);
    deg_count_kernel<<<(N_EDGES + 255) / 256, 256, 0, stream>>>(ei, deg);
    scanA_kernel<<<NB_SCAN, SCAN_CHUNK, 0, stream>>>(deg, bsum);
    scanB_kernel<<<1, 64, 0, stream>>>(bsum, boff, rowPtr);
    scanC_kernel<<<NB_SCAN, SCAN_CHUNK, 0, stream>>>(deg, boff, rowPtr, cursor);
    fill_kernel<<<(N_EDGES + 255) / 256, 256, 0, stream>>>(ei, ea, cursor, edgeP);

    // ----- degree counting sort (contention-free, parallel scan) -> perm -----
    hipMemsetAsync(perm, 0, PERM_PAD * sizeof(int), stream);   // pad tail -> node 0
    s1_blockhist_kernel<<<NB_SCAN, DBINS, 0, stream>>>(deg, blockHist);
    s2a_colscan_kernel<<<4, 256, 0, stream>>>(blockHist, binTot);
    s2b_binscan_kernel<<<1, DBINS, 0, stream>>>(binTot, binStart);
    s3_scatter_kernel<<<NB_SCAN, DBINS, 0, stream>>>(deg, blockHist, binStart, perm);

    // ----- weight packing (single dispatch) -----
    pack_all_kernel<<<80, 256, 0, stream>>>(W1_s, W2_s, Wp1, wpk);

    // ----- layer 0 (NODE_IN -> HID) -----
    hipMemsetAsync(aggr0, 0, (size_t)N_NODES * NODE_IN * sizeof(float), stream);
    scatter0_kernel<<<(N_EDGES * NODE_IN) / 256, 256, 0, stream>>>(x, ei, ea, We0, be0, aggr0);
    mlp0_kernel<<<N_NODES / 32, 256, 0, stream>>>(x, aggr0, W10, b10, W20, b20, h16A);

    // ----- layers 1..3 (HID -> HID), ping-pong -----
    const size_t WSLOT = 16384;
    unsigned short* hin = h16A; unsigned short* hout_ = h16B;
    for (int l = 0; l < 3; l++) {
        gine_mfma_kernel<false><<<NBLK64, 256, 0, stream>>>(
            hin, rowPtr, edgeP, perm,
            We_s + l * HID, be_s + l * HID,
            wpk + (0 + l) * WSLOT, wpk + (4 + l) * WSLOT, b1_s + l * HID,
            wpk + (8 + l) * WSLOT, wpk + (12 + l) * WSLOT, b2_s + l * HID,
            hout_, nullptr, nullptr, nullptr, nullptr, nullptr);
        unsigned short* tmp = hin; hin = hout_; hout_ = tmp;
    }
    // hin == h16B after 3 swaps

    // ----- layer 4 fused with pred GEMM -----
    {
        const int l = 3;
        gine_mfma_kernel<true><<<NBLK64, 256, 0, stream>>>(
            hin, rowPtr, edgeP, perm,
            We_s + l * HID, be_s + l * HID,
            wpk + (0 + l) * WSLOT, wpk + (4 + l) * WSLOT, b1_s + l * HID,
            wpk + (8 + l) * WSLOT, wpk + (12 + l) * WSLOT, b2_s + l * HID,
            nullptr, wpk + 16 * WSLOT, wpk + 17 * WSLOT,
            wpk + 18 * WSLOT, wpk + 19 * WSLOT, Pbuf);
    }

    // ----- edge predictor tail -----
    pred_edge_kernel<<<N_EDGES / 8, 256, 0, stream>>>(Pbuf, ei, bp1, Wp2, bp2, out);
}

// Round 17
// 863.008 us; speedup vs baseline: 1.0006x; 1.0006x over previous
//
#include <hip/hip_runtime.h>

#define N_NODES 100000
#define N_EDGES 500000
#define NODE_IN 16
#define HID 128
#define LPAD 140          // LDS row stride (floats)
#define SCAN_CHUNK 1024
#define NB_SCAN ((N_NODES + SCAN_CHUNK - 1) / SCAN_CHUNK)   // 98
#define DBINS 1024
#define NBLK64 1563       // ceil(N_NODES/64)
#define PERM_PAD (NBLK64 * 64)   // 100032

typedef __attribute__((ext_vector_type(8))) short short8;   // 8×16b in 4 VGPRs
typedef __attribute__((ext_vector_type(4))) float f32x4;    // MFMA accumulator

__device__ __forceinline__ float elu_f(float v) {
    return v > 0.f ? v : __expf(v) - 1.f;
}

// bf16 pack/unpack (rne)
__device__ __forceinline__ unsigned short f2b(float f) {
    unsigned int u = __float_as_uint(f);
    unsigned int r = (u + 0x7fffu + ((u >> 16) & 1u)) >> 16;
    return (unsigned short)r;
}
__device__ __forceinline__ float b2f(unsigned short h) {
    return __uint_as_float((unsigned int)h << 16);
}
// fp16 pack/unpack
__device__ __forceinline__ unsigned short f2h(float f) {
    _Float16 h = (_Float16)f;
    unsigned short u;
    __builtin_memcpy(&u, &h, 2);
    return u;
}
__device__ __forceinline__ float h2f(unsigned short u) {
    _Float16 h;
    __builtin_memcpy(&h, &u, 2);
    return (float)h;
}

// ===========================================================================
// CSR-by-dst build
// ===========================================================================
__global__ void deg_count_kernel(const int* __restrict__ ei, int* __restrict__ deg) {
    int e = blockIdx.x * 256 + threadIdx.x;
    if (e < N_EDGES) atomicAdd(&deg[ei[N_EDGES + e]], 1);
}

__global__ __launch_bounds__(1024) void scanA_kernel(const int* __restrict__ deg, int* __restrict__ bsum) {
    __shared__ int s[SCAN_CHUNK];
    int i = blockIdx.x * SCAN_CHUNK + threadIdx.x;
    s[threadIdx.x] = (i < N_NODES) ? deg[i] : 0;
    __syncthreads();
    for (int off = SCAN_CHUNK / 2; off > 0; off >>= 1) {
        if (threadIdx.x < off) s[threadIdx.x] += s[threadIdx.x + off];
        __syncthreads();
    }
    if (threadIdx.x == 0) bsum[blockIdx.x] = s[0];
}

__global__ void scanB_kernel(const int* __restrict__ bsum, int* __restrict__ boff,
                             int* __restrict__ rowPtr) {
    if (threadIdx.x == 0 && blockIdx.x == 0) {
        int r = 0;
        for (int i = 0; i < NB_SCAN; i++) { boff[i] = r; r += bsum[i]; }
        rowPtr[N_NODES] = N_EDGES;
    }
}

__global__ __launch_bounds__(1024) void scanC_kernel(const int* __restrict__ deg,
                                                     const int* __restrict__ boff,
                                                     int* __restrict__ rowPtr,
                                                     int* __restrict__ cursor) {
    __shared__ int bufA[SCAN_CHUNK], bufB[SCAN_CHUNK];
    int i = blockIdx.x * SCAN_CHUNK + threadIdx.x;
    int t = threadIdx.x;
    bufA[t] = (i < N_NODES) ? deg[i] : 0;
    __syncthreads();
    int* src = bufA; int* dst = bufB;
    for (int off = 1; off < SCAN_CHUNK; off <<= 1) {
        dst[t] = (t >= off) ? (src[t - off] + src[t]) : src[t];
        __syncthreads();
        int* tmp = src; src = dst; dst = tmp;
    }
    if (i < N_NODES) {
        int excl = (t == 0) ? 0 : src[t - 1];
        int v = excl + boff[blockIdx.x];
        rowPtr[i] = v;
        cursor[i] = v;
    }
}

// payload reorder: (src, ea) packed int2 in CSR(dst) order
__global__ void fill_kernel(const int* __restrict__ ei, const float* __restrict__ ea,
                            int* __restrict__ cursor, int2* __restrict__ edgeP) {
    int e = blockIdx.x * 256 + threadIdx.x;
    if (e < N_EDGES) {
        int d = ei[N_EDGES + e];
        int p = atomicAdd(&cursor[d], 1);
        edgeP[p] = make_int2(ei[e], __float_as_int(ea[e]));
    }
}

// ===========================================================================
// Degree counting sort, contention-free, parallel scan
// ===========================================================================
__global__ __launch_bounds__(1024) void s1_blockhist_kernel(const int* __restrict__ deg,
                                                            int* __restrict__ blockHist) {
    __shared__ int h[DBINS];
    int t = threadIdx.x, b = blockIdx.x;
    h[t] = 0;
    __syncthreads();
    int i = b * SCAN_CHUNK + t;
    if (i < N_NODES) atomicAdd(&h[min(deg[i], DBINS - 1)], 1);
    __syncthreads();
    blockHist[b * DBINS + t] = h[t];
}

// s2a: per-bin column exclusive prefix over the 98 blocks (1024 indep columns)
__global__ __launch_bounds__(256) void s2a_colscan_kernel(int* __restrict__ blockHist,
                                                          int* __restrict__ binTot) {
    int k = blockIdx.x * 256 + threadIdx.x;
    if (k >= DBINS) return;
    int r = 0;
#pragma unroll 7
    for (int b = 0; b < NB_SCAN; b++) {
        int v = blockHist[b * DBINS + k];
        blockHist[b * DBINS + k] = r;
        r += v;
    }
    binTot[k] = r;
}

// s2b: exclusive scan of 1024 bin totals (single block, LDS)
__global__ __launch_bounds__(1024) void s2b_binscan_kernel(const int* __restrict__ binTot,
                                                           int* __restrict__ binStart) {
    __shared__ int bufA[DBINS], bufB[DBINS];
    int k = threadIdx.x;
    bufA[k] = binTot[k];
    __syncthreads();
    int* src = bufA; int* dst = bufB;
    for (int off = 1; off < DBINS; off <<= 1) {
        dst[k] = (k >= off) ? (src[k - off] + src[k]) : src[k];
        __syncthreads();
        int* tmp = src; src = dst; dst = tmp;
    }
    binStart[k] = (k == 0) ? 0 : src[k - 1];
}

// s3: scatter via LDS cursors (binStart fused in)
__global__ __launch_bounds__(1024) void s3_scatter_kernel(const int* __restrict__ deg,
                                                          const int* __restrict__ blockHist,
                                                          const int* __restrict__ binStart,
                                                          int* __restrict__ perm) {
    __shared__ int cur[DBINS];
    int t = threadIdx.x, b = blockIdx.x;
    cur[t] = blockHist[b * DBINS + t] + binStart[t];
    __syncthreads();
    int i = b * SCAN_CHUNK + t;
    if (i < N_NODES) {
        int k = min(deg[i], DBINS - 1);
        int p = atomicAdd(&cur[k], 1);            // LDS atomic, intra-block only
        perm[p] = i;
    }
}

// ===========================================================================
// Merged weight pack: all 10 matrices in one dispatch.
// ===========================================================================
__global__ __launch_bounds__(256) void pack_all_kernel(
    const float* __restrict__ W1_s, const float* __restrict__ W2_s,
    const float* __restrict__ Wp1, unsigned short* __restrict__ wpk)
{
    int gid = blockIdx.x * 256 + threadIdx.x;   // 10 * 2048
    if (gid >= 10 * 2048) return;
    int m = gid >> 11, r = gid & 2047;
    const float* W; int K_off = 0; int hi_slot, lo_slot;
    if (m < 4)       { W = W1_s + (size_t)m * 16384;       hi_slot = m;          lo_slot = 4 + m; }
    else if (m < 8)  { W = W2_s + (size_t)(m - 4) * 16384; hi_slot = 8 + (m - 4); lo_slot = 12 + (m - 4); }
    else if (m == 8) { W = Wp1; K_off = 0;   hi_slot = 16; lo_slot = 17; }
    else             { W = Wp1; K_off = 128; hi_slot = 18; lo_slot = 19; }
    int lane = r & 63, tl = (r >> 6) & 7, ch = r >> 9;
    int kb = ch * 32 + (lane >> 4) * 8;
    int n  = tl * 16 + (lane & 15);
    unsigned short* hi = wpk + (size_t)hi_slot * 16384;
    unsigned short* lo = wpk + (size_t)lo_slot * 16384;
    for (int j = 0; j < 8; j++) {
        float w = W[(size_t)(K_off + kb + j) * 128 + n];
        unsigned short h = f2b(w);
        hi[(size_t)r * 8 + j] = h;
        lo[(size_t)r * 8 + j] = f2b(w - b2f(h));
    }
}

// ===========================================================================
// Layer 0 scatter (fp32 aggr, NODE_IN=16)
// ===========================================================================
__global__ __launch_bounds__(256) void scatter0_kernel(
    const float* __restrict__ x, const int* __restrict__ ei,
    const float* __restrict__ ea, const float* __restrict__ We0,
    const float* __restrict__ be0, float* __restrict__ aggr)
{
    int idx = blockIdx.x * 256 + threadIdx.x;
    int e = idx >> 4, c = idx & 15;
    int s = ei[e], d = ei[N_EDGES + e];
    float m = x[s * NODE_IN + c] + ea[e] * We0[c] + be0[c];
    m = fmaxf(m, 0.f);
    atomicAdd(&aggr[d * NODE_IN + c], m);
}

// ---------------------------------------------------------------------------
__device__ __forceinline__ void fma4x4(float (&acc)[4][4],
    const float4& r0, const float4& r1, const float4& r2, const float4& r3,
    const float4& w0, const float4& w1, const float4& w2, const float4& w3)
{
    float r[4][4] = {{r0.x, r0.y, r0.z, r0.w}, {r1.x, r1.y, r1.z, r1.w},
                     {r2.x, r2.y, r2.z, r2.w}, {r3.x, r3.y, r3.z, r3.w}};
    float w[4][4] = {{w0.x, w0.y, w0.z, w0.w}, {w1.x, w1.y, w1.z, w1.w},
                     {w2.x, w2.y, w2.z, w2.w}, {w3.x, w3.y, w3.z, w3.w}};
#pragma unroll
    for (int i = 0; i < 4; i++)
#pragma unroll
        for (int k = 0; k < 4; k++)
#pragma unroll
            for (int c = 0; c < 4; c++)
                acc[i][c] = fmaf(r[i][k], w[k][c], acc[i][c]);
}

// ===========================================================================
// Layer 0 MLP (fp32 vector) -> writes h as fp16
// ===========================================================================
__global__ __launch_bounds__(256) void mlp0_kernel(
    const float* __restrict__ x, const float* __restrict__ aggr,
    const float* __restrict__ W1, const float* __restrict__ b1,
    const float* __restrict__ W2, const float* __restrict__ b2,
    unsigned short* __restrict__ h)
{
    __shared__ float in0[32][20];
    __shared__ float mid[32][HID];
    const int t = threadIdx.x;
    const int q = t & 31, g = t >> 5;
    const int c0 = q * 4;
    const int base = blockIdx.x * 32;

    for (int i = t; i < 32 * NODE_IN; i += 256) {
        int r = i >> 4, cc = i & 15;
        int n = base + r;
        in0[r][cc] = x[n * NODE_IN + cc] + aggr[n * NODE_IN + cc];
    }
    __syncthreads();

    float4 bb = *(const float4*)&b1[c0];
    float acc[4][4];
#pragma unroll
    for (int i = 0; i < 4; i++) { acc[i][0] = bb.x; acc[i][1] = bb.y; acc[i][2] = bb.z; acc[i][3] = bb.w; }
    for (int k = 0; k < NODE_IN; k += 4) {
        float4 r0 = *(const float4*)&in0[g * 4 + 0][k];
        float4 r1 = *(const float4*)&in0[g * 4 + 1][k];
        float4 r2 = *(const float4*)&in0[g * 4 + 2][k];
        float4 r3 = *(const float4*)&in0[g * 4 + 3][k];
        float4 w0 = *(const float4*)&W1[(k + 0) * HID + c0];
        float4 w1 = *(const float4*)&W1[(k + 1) * HID + c0];
        float4 w2 = *(const float4*)&W1[(k + 2) * HID + c0];
        float4 w3 = *(const float4*)&W1[(k + 3) * HID + c0];
        fma4x4(acc, r0, r1, r2, r3, w0, w1, w2, w3);
    }
#pragma unroll
    for (int i = 0; i < 4; i++)
        *(float4*)&mid[g * 4 + i][c0] = make_float4(elu_f(acc[i][0]), elu_f(acc[i][1]),
                                                    elu_f(acc[i][2]), elu_f(acc[i][3]));
    __syncthreads();

    float4 bb2 = *(const float4*)&b2[c0];
    float acc2[4][4];
#pragma unroll
    for (int i = 0; i < 4; i++) { acc2[i][0] = bb2.x; acc2[i][1] = bb2.y; acc2[i][2] = bb2.z; acc2[i][3] = bb2.w; }
    for (int k = 0; k < HID; k += 4) {
        float4 r0 = *(const float4*)&mid[g * 4 + 0][k];
        float4 r1 = *(const float4*)&mid[g * 4 + 1][k];
        float4 r2 = *(const float4*)&mid[g * 4 + 2][k];
        float4 r3 = *(const float4*)&mid[g * 4 + 3][k];
        float4 w0 = *(const float4*)&W2[(k + 0) * HID + c0];
        float4 w1 = *(const float4*)&W2[(k + 1) * HID + c0];
        float4 w2 = *(const float4*)&W2[(k + 2) * HID + c0];
        float4 w3 = *(const float4*)&W2[(k + 3) * HID + c0];
        fma4x4(acc2, r0, r1, r2, r3, w0, w1, w2, w3);
    }
#pragma unroll
    for (int i = 0; i < 4; i++) {
        ushort4 o;
        o.x = f2h(elu_f(acc2[i][0])); o.y = f2h(elu_f(acc2[i][1]));
        o.z = f2h(elu_f(acc2[i][2])); o.w = f2h(elu_f(acc2[i][3]));
        *(ushort4*)&h[(size_t)(base + g * 4 + i) * HID + c0] = o;
    }
}

// ---------------------------------------------------------------------------
// A-fragment load+split from LDS (fp32 -> hi/lo bf16), layout per m120
// ---------------------------------------------------------------------------
__device__ __forceinline__ void afrag_split(const float (&buf)[16][LPAD], int lane,
                                            short8 (&ah)[4], short8 (&al)[4])
{
    const int m = lane & 15, s8 = (lane >> 4) * 8;
#pragma unroll
    for (int ch = 0; ch < 4; ch++) {
        float4 a0 = *(const float4*)&buf[m][ch * 32 + s8];
        float4 a1 = *(const float4*)&buf[m][ch * 32 + s8 + 4];
        float av[8] = {a0.x, a0.y, a0.z, a0.w, a1.x, a1.y, a1.z, a1.w};
#pragma unroll
        for (int j = 0; j < 8; j++) {
            unsigned short h = f2b(av[j]);
            ah[ch][j] = (short)h;
            al[ch][j] = (short)f2b(av[j] - b2f(h));
        }
    }
}

// ===========================================================================
// Fused GINE HID layer, v14: 12-SLOT gather pipeline (3 steps x 4 rows;
// fits the 128-VGPR/4-wave budget — no spill). 4 waves/block x 16 sorted
// nodes; fp16 h storage; split-bf16 MFMA MLP.
// ===========================================================================
template <bool PRED>
__global__ __launch_bounds__(256, 4) void gine_mfma_kernel(
    const unsigned short* __restrict__ hin, const int* __restrict__ rowPtr,
    const int2* __restrict__ edgeP, const int* __restrict__ perm,
    const float* __restrict__ We, const float* __restrict__ be,
    const unsigned short* __restrict__ W1h, const unsigned short* __restrict__ W1l,
    const float* __restrict__ b1,
    const unsigned short* __restrict__ W2h, const unsigned short* __restrict__ W2l,
    const float* __restrict__ b2,
    unsigned short* __restrict__ hout,
    const unsigned short* __restrict__ P1h, const unsigned short* __restrict__ P1l,
    const unsigned short* __restrict__ P2h, const unsigned short* __restrict__ P2l,
    unsigned short* __restrict__ Pbuf)
{
    __shared__ float bufAll[4][16][LPAD];   // 35.84 KB, one slice per wave
    const int w = threadIdx.x >> 6;
    const int lane = threadIdx.x & 63;
    float (&buf)[16][LPAD] = bufAll[w];
    const int qg = lane & 15, rg = lane >> 4;
    const int c0 = qg * 8;                  // 16 lanes x 8 cols
    const int base = blockIdx.x * 64 + w * 16;

    float wev[8], bev[8];
#pragma unroll
    for (int j = 0; j < 8; j++) { wev[j] = We[c0 + j]; bev[j] = be[c0 + j]; }

    // ---- stage 1: 12-slot pipelined gather over degree-sorted nodes ----
    int nn[4], s0[4], e0[4];
    float acc[4][8];
#pragma unroll
    for (int i = 0; i < 4; i++) {
        nn[i] = perm[base + rg * 4 + i];
        s0[i] = rowPtr[nn[i]];
        e0[i] = rowPtr[nn[i] + 1];
        short8 h0 = *(const short8*)&hin[(size_t)nn[i] * HID + c0];
#pragma unroll
        for (int j = 0; j < 8; j++) acc[i][j] = h2f((unsigned short)h0[j]);
    }
    int maxd = 0;
#pragma unroll
    for (int i = 0; i < 4; i++) maxd = max(maxd, e0[i] - s0[i]);

    int idx[12]; float av[12]; bool act[12];
#pragma unroll
    for (int u = 0; u < 3; u++)
#pragma unroll
        for (int i = 0; i < 4; i++) {
            int slot = u * 4 + i;
            int j = s0[i] + u;
            act[slot] = j < e0[i];
            int jc = act[slot] ? j : (N_EDGES - 1);
            int2 ep = edgeP[jc];
            idx[slot] = ep.x;
            av[slot]  = __int_as_float(ep.y);
        }

    for (int sb = 0; sb < maxd; sb += 3) {
        short8 hraw[12];
#pragma unroll
        for (int s = 0; s < 12; s++)
            hraw[s] = *(const short8*)&hin[(size_t)idx[s] * HID + c0];

        int nidx[12]; float nav[12]; bool nact[12];
#pragma unroll
        for (int u = 0; u < 3; u++)
#pragma unroll
            for (int i = 0; i < 4; i++) {
                int slot = u * 4 + i;
                int j = s0[i] + sb + 3 + u;
                nact[slot] = j < e0[i];
                int jc = nact[slot] ? j : (N_EDGES - 1);
                int2 ep = edgeP[jc];
                nidx[slot] = ep.x;
                nav[slot]  = __int_as_float(ep.y);
            }

#pragma unroll
        for (int u = 0; u < 3; u++)
#pragma unroll
            for (int i = 0; i < 4; i++) {
                int slot = u * 4 + i;
                if (act[slot]) {
#pragma unroll
                    for (int j = 0; j < 8; j++) {
                        float hv = h2f((unsigned short)hraw[slot][j]);
                        acc[i][j] += fmaxf(fmaf(av[slot], wev[j], bev[j]) + hv, 0.f);
                    }
                }
            }
#pragma unroll
        for (int s = 0; s < 12; s++) {
            idx[s] = nidx[s]; av[s] = nav[s]; act[s] = nact[s];
        }
    }
#pragma unroll
    for (int i = 0; i < 4; i++) {
        *(float4*)&buf[rg * 4 + i][c0]     = make_float4(acc[i][0], acc[i][1], acc[i][2], acc[i][3]);
        *(float4*)&buf[rg * 4 + i][c0 + 4] = make_float4(acc[i][4], acc[i][5], acc[i][6], acc[i][7]);
    }
    __syncthreads();   // waves have equal degree (sorted) -> negligible convoy

    const int col16 = lane & 15, r0 = (lane >> 4) * 4;

    // ---- stage 2: mid = elu(in @ W1 + b1), split-bf16 MFMA, in-place ----
    {
        short8 ah[4], al[4];
        afrag_split(buf, lane, ah, al);
        float res[8][4];
#pragma unroll
        for (int tl = 0; tl < 8; tl++) {
            int col = tl * 16 + col16;
            float bv = b1[col];
            f32x4 c = {bv, bv, bv, bv};
#pragma unroll
            for (int ch = 0; ch < 4; ch++) {
                int off = ((ch * 8 + tl) * 64 + lane) * 8;
                short8 bh = *(const short8*)&W1h[off];
                short8 bl = *(const short8*)&W1l[off];
                c = __builtin_amdgcn_mfma_f32_16x16x32_bf16(ah[ch], bh, c, 0, 0, 0);
                c = __builtin_amdgcn_mfma_f32_16x16x32_bf16(al[ch], bh, c, 0, 0, 0);
                c = __builtin_amdgcn_mfma_f32_16x16x32_bf16(ah[ch], bl, c, 0, 0, 0);
            }
#pragma unroll
            for (int r = 0; r < 4; r++) res[tl][r] = elu_f(c[r]);
        }
        __syncthreads();
#pragma unroll
        for (int tl = 0; tl < 8; tl++)
#pragma unroll
            for (int r = 0; r < 4; r++)
                buf[r0 + r][tl * 16 + col16] = res[tl][r];
    }
    __syncthreads();

    // ---- stage 3: h = elu(mid @ W2 + b2), in-place ----
    {
        short8 ah[4], al[4];
        afrag_split(buf, lane, ah, al);
        float res[8][4];
#pragma unroll
        for (int tl = 0; tl < 8; tl++) {
            int col = tl * 16 + col16;
            float bv = b2[col];
            f32x4 c = {bv, bv, bv, bv};
#pragma unroll
            for (int ch = 0; ch < 4; ch++) {
                int off = ((ch * 8 + tl) * 64 + lane) * 8;
                short8 bh = *(const short8*)&W2h[off];
                short8 bl = *(const short8*)&W2l[off];
                c = __builtin_amdgcn_mfma_f32_16x16x32_bf16(ah[ch], bh, c, 0, 0, 0);
                c = __builtin_amdgcn_mfma_f32_16x16x32_bf16(al[ch], bh, c, 0, 0, 0);
                c = __builtin_amdgcn_mfma_f32_16x16x32_bf16(ah[ch], bl, c, 0, 0, 0);
            }
#pragma unroll
            for (int r = 0; r < 4; r++) res[tl][r] = elu_f(c[r]);
        }
        __syncthreads();
#pragma unroll
        for (int tl = 0; tl < 8; tl++)
#pragma unroll
            for (int r = 0; r < 4; r++)
                buf[r0 + r][tl * 16 + col16] = res[tl][r];
    }
    __syncthreads();

    if constexpr (!PRED) {
        // fp16 store of h (row-scattered by perm; 256 B contiguous per row)
#pragma unroll
        for (int i = 0; i < 4; i++) {
            short8 o;
#pragma unroll
            for (int j = 0; j < 8; j++) o[j] = (short)f2h(buf[rg * 4 + i][c0 + j]);
            *(short8*)&hout[(size_t)nn[i] * HID + c0] = o;
        }
    } else {
        // P1|P2 = h @ Wp1 halves, emit bf16 packed rows (perm-indexed)
        short8 ah[4], al[4];
        afrag_split(buf, lane, ah, al);
        int pn[4];
#pragma unroll
        for (int r = 0; r < 4; r++) pn[r] = perm[base + r0 + r];
#pragma unroll
        for (int tl = 0; tl < 8; tl++) {
            int col = tl * 16 + col16;
            f32x4 c1 = {0.f, 0.f, 0.f, 0.f};
            f32x4 c2 = {0.f, 0.f, 0.f, 0.f};
#pragma unroll
            for (int ch = 0; ch < 4; ch++) {
                int off = ((ch * 8 + tl) * 64 + lane) * 8;
                short8 bh1 = *(const short8*)&P1h[off];
                short8 bl1 = *(const short8*)&P1l[off];
                c1 = __builtin_amdgcn_mfma_f32_16x16x32_bf16(ah[ch], bh1, c1, 0, 0, 0);
                c1 = __builtin_amdgcn_mfma_f32_16x16x32_bf16(al[ch], bh1, c1, 0, 0, 0);
                c1 = __builtin_amdgcn_mfma_f32_16x16x32_bf16(ah[ch], bl1, c1, 0, 0, 0);
                short8 bh2 = *(const short8*)&P2h[off];
                short8 bl2 = *(const short8*)&P2l[off];
                c2 = __builtin_amdgcn_mfma_f32_16x16x32_bf16(ah[ch], bh2, c2, 0, 0, 0);
                c2 = __builtin_amdgcn_mfma_f32_16x16x32_bf16(al[ch], bh2, c2, 0, 0, 0);
                c2 = __builtin_amdgcn_mfma_f32_16x16x32_bf16(ah[ch], bl2, c2, 0, 0, 0);
            }
#pragma unroll
            for (int r = 0; r < 4; r++) {
                size_t n = (size_t)pn[r];
                Pbuf[n * 256 + col]       = f2b(c1[r]);
                Pbuf[n * 256 + 128 + col] = f2b(c2[r]);
            }
        }
    }
}

// ===========================================================================
// Edge predictor tail
// ===========================================================================
__global__ __launch_bounds__(256) void pred_edge_kernel(
    const unsigned short* __restrict__ Pbuf, const int* __restrict__ ei,
    const float* __restrict__ bp1, const float* __restrict__ Wp2,
    const float* __restrict__ bp2, float* __restrict__ out)
{
    const int t = threadIdx.x;
    const int lane = t & 31;
    const int eloc = t >> 5;
    const int e = blockIdx.x * 8 + eloc;
    const int c0 = lane * 4;

    int s = ei[e], d = ei[N_EDGES + e];
    ushort4 ua = *(const ushort4*)&Pbuf[(size_t)s * 256 + c0];
    ushort4 ub = *(const ushort4*)&Pbuf[(size_t)d * 256 + 128 + c0];
    float4 bb = *(const float4*)&bp1[c0];
    float4 w = *(const float4*)&Wp2[c0];
    float r = elu_f(b2f(ua.x) + b2f(ub.x) + bb.x) * w.x
            + elu_f(b2f(ua.y) + b2f(ub.y) + bb.y) * w.y
            + elu_f(b2f(ua.z) + b2f(ub.z) + bb.z) * w.z
            + elu_f(b2f(ua.w) + b2f(ub.w) + bb.w) * w.w;
#pragma unroll
    for (int off = 16; off > 0; off >>= 1) r += __shfl_down(r, off, 32);
    if (lane == 0) out[e] = r + bp2[0];
}

// ===========================================================================
extern "C" void kernel_launch(void* const* d_in, const int* in_sizes, int n_in,
                              void* d_out, int out_size, void* d_ws, size_t ws_size,
                              hipStream_t stream) {
    const float* x    = (const float*)d_in[0];
    const int*   ei   = (const int*)d_in[1];
    const float* ea   = (const float*)d_in[2];
    const float* We0  = (const float*)d_in[3];
    const float* be0  = (const float*)d_in[4];
    const float* W10  = (const float*)d_in[5];
    const float* b10  = (const float*)d_in[6];
    const float* W20  = (const float*)d_in[7];
    const float* b20  = (const float*)d_in[8];
    const float* We_s = (const float*)d_in[9];
    const float* be_s = (const float*)d_in[10];
    const float* W1_s = (const float*)d_in[11];
    const float* b1_s = (const float*)d_in[12];
    const float* W2_s = (const float*)d_in[13];
    const float* b2_s = (const float*)d_in[14];
    const float* Wp1  = (const float*)d_in[15];
    const float* bp1  = (const float*)d_in[16];
    const float* Wp2  = (const float*)d_in[17];
    const float* bp2  = (const float*)d_in[18];
    float* out = (float*)d_out;

    // workspace: h16A (25.6MB) | h16B (25.6MB) | Pbuf (51.2MB) | R
    unsigned short* h16A = (unsigned short*)d_ws;
    unsigned short* h16B = h16A + (size_t)N_NODES * HID;
    unsigned short* Pbuf = h16B + (size_t)N_NODES * HID;
    float* R = (float*)(Pbuf + (size_t)N_NODES * 256);

    float* aggr0 = R;                                  // N*16 f32
    int* deg     = (int*)(aggr0 + (size_t)N_NODES * NODE_IN);
    int* rowPtr  = deg + N_NODES;                      // N+1 ints
    int* cursor  = rowPtr + N_NODES + 1;
    int2* edgeP  = (int2*)(cursor + N_NODES);          // 500k int2
    int* bsum    = (int*)(edgeP + N_EDGES);
    int* boff    = bsum + NB_SCAN;
    int* perm    = boff + NB_SCAN;                     // PERM_PAD ints
    int* blockHist = perm + PERM_PAD;                  // 98*1024
    int* binTot   = blockHist + NB_SCAN * DBINS;       // 1024
    int* binStart = binTot + DBINS;                    // 1024

    // packed weights: 20 slots x 16384 ushorts = 640 KB, at R+24MB
    unsigned short* wpk = (unsigned short*)(R + (size_t)6 * 1024 * 1024);

    // ----- CSR build -----
    hipMemsetAsync(deg, 0, N_NODES * sizeof(int), stream);
    deg_count_kernel<<<(N_EDGES + 255) / 256, 256, 0, stream>>>(ei, deg);
    scanA_kernel<<<NB_SCAN, SCAN_CHUNK, 0, stream>>>(deg, bsum);
    scanB_kernel<<<1, 64, 0, stream>>>(bsum, boff, rowPtr);
    scanC_kernel<<<NB_SCAN, SCAN_CHUNK, 0, stream>>>(deg, boff, rowPtr, cursor);
    fill_kernel<<<(N_EDGES + 255) / 256, 256, 0, stream>>>(ei, ea, cursor, edgeP);

    // ----- degree counting sort (contention-free, parallel scan) -> perm -----
    hipMemsetAsync(perm, 0, PERM_PAD * sizeof(int), stream);   // pad tail -> node 0
    s1_blockhist_kernel<<<NB_SCAN, DBINS, 0, stream>>>(deg, blockHist);
    s2a_colscan_kernel<<<4, 256, 0, stream>>>(blockHist, binTot);
    s2b_binscan_kernel<<<1, DBINS, 0, stream>>>(binTot, binStart);
    s3_scatter_kernel<<<NB_SCAN, DBINS, 0, stream>>>(deg, blockHist, binStart, perm);

    // ----- weight packing (single dispatch) -----
    pack_all_kernel<<<80, 256, 0, stream>>>(W1_s, W2_s, Wp1, wpk);

    // ----- layer 0 (NODE_IN -> HID) -----
    hipMemsetAsync(aggr0, 0, (size_t)N_NODES * NODE_IN * sizeof(float), stream);
    scatter0_kernel<<<(N_EDGES * NODE_IN) / 256, 256, 0, stream>>>(x, ei, ea, We0, be0, aggr0);
    mlp0_kernel<<<N_NODES / 32, 256, 0, stream>>>(x, aggr0, W10, b10, W20, b20, h16A);

    // ----- layers 1..3 (HID -> HID), ping-pong -----
    const size_t WSLOT = 16384;
    unsigned short* hin = h16A; unsigned short* hout_ = h16B;
    for (int l = 0; l < 3; l++) {
        gine_mfma_kernel<false><<<NBLK64, 256, 0, stream>>>(
            hin, rowPtr, edgeP, perm,
            We_s + l * HID, be_s + l * HID,
            wpk + (0 + l) * WSLOT, wpk + (4 + l) * WSLOT, b1_s + l * HID,
            wpk + (8 + l) * WSLOT, wpk + (12 + l) * WSLOT, b2_s + l * HID,
            hout_, nullptr, nullptr, nullptr, nullptr, nullptr);
        unsigned short* tmp = hin; hin = hout_; hout_ = tmp;
    }
    // hin == h16B after 3 swaps

    // ----- layer 4 fused with pred GEMM -----
    {
        const int l = 3;
        gine_mfma_kernel<true><<<NBLK64, 256, 0, stream>>>(
            hin, rowPtr, edgeP, perm,
            We_s + l * HID, be_s + l * HID,
            wpk + (0 + l) * WSLOT, wpk + (4 + l) * WSLOT, b1_s + l * HID,
            wpk + (8 + l) * WSLOT, wpk + (12 + l) * WSLOT, b2_s + l * HID,
            nullptr, wpk + 16 * WSLOT, wpk + 17 * WSLOT,
            wpk + 18 * WSLOT, wpk + 19 * WSLOT, Pbuf);
    }

    // ----- edge predictor tail -----
    pred_edge_kernel<<<N_EDGES / 8, 256, 0, stream>>>(Pbuf, ei, bp1, Wp2, bp2, out);
}

// Round 18
// 608.418 us; speedup vs baseline: 1.4193x; 1.4184x over previous
//
#include <hip/hip_runtime.h>

#define N_NODES 100000
#define N_EDGES 500000
#define NODE_IN 16
#define HID 128
#define LPAD 140          // LDS row stride (floats)
#define SCAN_CHUNK 1024
#define NB_SCAN ((N_NODES + SCAN_CHUNK - 1) / SCAN_CHUNK)   // 98
#define DBINS 1024
#define NBLK64 1563       // ceil(N_NODES/64)
#define PERM_PAD (NBLK64 * 64)   // 100032

typedef __attribute__((ext_vector_type(8))) short short8;   // 8×16b in 4 VGPRs
typedef __attribute__((ext_vector_type(4))) float f32x4;    // MFMA accumulator

__device__ __forceinline__ float elu_f(float v) {
    return v > 0.f ? v : __expf(v) - 1.f;
}

// bf16 pack/unpack (rne)
__device__ __forceinline__ unsigned short f2b(float f) {
    unsigned int u = __float_as_uint(f);
    unsigned int r = (u + 0x7fffu + ((u >> 16) & 1u)) >> 16;
    return (unsigned short)r;
}
__device__ __forceinline__ float b2f(unsigned short h) {
    return __uint_as_float((unsigned int)h << 16);
}
// fp16 pack/unpack
__device__ __forceinline__ unsigned short f2h(float f) {
    _Float16 h = (_Float16)f;
    unsigned short u;
    __builtin_memcpy(&u, &h, 2);
    return u;
}
__device__ __forceinline__ float h2f(unsigned short u) {
    _Float16 h;
    __builtin_memcpy(&h, &u, 2);
    return (float)h;
}

// ===========================================================================
// CSR-by-dst build
// ===========================================================================
__global__ void deg_count_kernel(const int* __restrict__ ei, int* __restrict__ deg) {
    int e = blockIdx.x * 256 + threadIdx.x;
    if (e < N_EDGES) atomicAdd(&deg[ei[N_EDGES + e]], 1);
}

__global__ __launch_bounds__(1024) void scanA_kernel(const int* __restrict__ deg, int* __restrict__ bsum) {
    __shared__ int s[SCAN_CHUNK];
    int i = blockIdx.x * SCAN_CHUNK + threadIdx.x;
    s[threadIdx.x] = (i < N_NODES) ? deg[i] : 0;
    __syncthreads();
    for (int off = SCAN_CHUNK / 2; off > 0; off >>= 1) {
        if (threadIdx.x < off) s[threadIdx.x] += s[threadIdx.x + off];
        __syncthreads();
    }
    if (threadIdx.x == 0) bsum[blockIdx.x] = s[0];
}

__global__ void scanB_kernel(const int* __restrict__ bsum, int* __restrict__ boff,
                             int* __restrict__ rowPtr) {
    if (threadIdx.x == 0 && blockIdx.x == 0) {
        int r = 0;
        for (int i = 0; i < NB_SCAN; i++) { boff[i] = r; r += bsum[i]; }
        rowPtr[N_NODES] = N_EDGES;
    }
}

__global__ __launch_bounds__(1024) void scanC_kernel(const int* __restrict__ deg,
                                                     const int* __restrict__ boff,
                                                     int* __restrict__ rowPtr,
                                                     int* __restrict__ cursor) {
    __shared__ int bufA[SCAN_CHUNK], bufB[SCAN_CHUNK];
    int i = blockIdx.x * SCAN_CHUNK + threadIdx.x;
    int t = threadIdx.x;
    bufA[t] = (i < N_NODES) ? deg[i] : 0;
    __syncthreads();
    int* src = bufA; int* dst = bufB;
    for (int off = 1; off < SCAN_CHUNK; off <<= 1) {
        dst[t] = (t >= off) ? (src[t - off] + src[t]) : src[t];
        __syncthreads();
        int* tmp = src; src = dst; dst = tmp;
    }
    if (i < N_NODES) {
        int excl = (t == 0) ? 0 : src[t - 1];
        int v = excl + boff[blockIdx.x];
        rowPtr[i] = v;
        cursor[i] = v;
    }
}

// payload reorder: (src, ea) packed int2 in CSR(dst) order; eorig = orig edge id
__global__ void fill_kernel(const int* __restrict__ ei, const float* __restrict__ ea,
                            int* __restrict__ cursor, int2* __restrict__ edgeP,
                            int* __restrict__ eorig) {
    int e = blockIdx.x * 256 + threadIdx.x;
    if (e < N_EDGES) {
        int d = ei[N_EDGES + e];
        int p = atomicAdd(&cursor[d], 1);
        edgeP[p] = make_int2(ei[e], __float_as_int(ea[e]));
        eorig[p] = e;
    }
}

// ===========================================================================
// Degree counting sort, contention-free, parallel scan
// ===========================================================================
__global__ __launch_bounds__(1024) void s1_blockhist_kernel(const int* __restrict__ deg,
                                                            int* __restrict__ blockHist) {
    __shared__ int h[DBINS];
    int t = threadIdx.x, b = blockIdx.x;
    h[t] = 0;
    __syncthreads();
    int i = b * SCAN_CHUNK + t;
    if (i < N_NODES) atomicAdd(&h[min(deg[i], DBINS - 1)], 1);
    __syncthreads();
    blockHist[b * DBINS + t] = h[t];
}

__global__ __launch_bounds__(256) void s2a_colscan_kernel(int* __restrict__ blockHist,
                                                          int* __restrict__ binTot) {
    int k = blockIdx.x * 256 + threadIdx.x;
    if (k >= DBINS) return;
    int r = 0;
#pragma unroll 7
    for (int b = 0; b < NB_SCAN; b++) {
        int v = blockHist[b * DBINS + k];
        blockHist[b * DBINS + k] = r;
        r += v;
    }
    binTot[k] = r;
}

__global__ __launch_bounds__(1024) void s2b_binscan_kernel(const int* __restrict__ binTot,
                                                           int* __restrict__ binStart) {
    __shared__ int bufA[DBINS], bufB[DBINS];
    int k = threadIdx.x;
    bufA[k] = binTot[k];
    __syncthreads();
    int* src = bufA; int* dst = bufB;
    for (int off = 1; off < DBINS; off <<= 1) {
        dst[k] = (k >= off) ? (src[k - off] + src[k]) : src[k];
        __syncthreads();
        int* tmp = src; src = dst; dst = tmp;
    }
    binStart[k] = (k == 0) ? 0 : src[k - 1];
}

__global__ __launch_bounds__(1024) void s3_scatter_kernel(const int* __restrict__ deg,
                                                          const int* __restrict__ blockHist,
                                                          const int* __restrict__ binStart,
                                                          int* __restrict__ perm) {
    __shared__ int cur[DBINS];
    int t = threadIdx.x, b = blockIdx.x;
    cur[t] = blockHist[b * DBINS + t] + binStart[t];
    __syncthreads();
    int i = b * SCAN_CHUNK + t;
    if (i < N_NODES) {
        int k = min(deg[i], DBINS - 1);
        int p = atomicAdd(&cur[k], 1);            // LDS atomic, intra-block only
        perm[p] = i;
    }
}

// ===========================================================================
// Merged weight pack: all 10 matrices in one dispatch.
// ===========================================================================
__global__ __launch_bounds__(256) void pack_all_kernel(
    const float* __restrict__ W1_s, const float* __restrict__ W2_s,
    const float* __restrict__ Wp1, unsigned short* __restrict__ wpk)
{
    int gid = blockIdx.x * 256 + threadIdx.x;   // 10 * 2048
    if (gid >= 10 * 2048) return;
    int m = gid >> 11, r = gid & 2047;
    const float* W; int K_off = 0; int hi_slot, lo_slot;
    if (m < 4)       { W = W1_s + (size_t)m * 16384;       hi_slot = m;          lo_slot = 4 + m; }
    else if (m < 8)  { W = W2_s + (size_t)(m - 4) * 16384; hi_slot = 8 + (m - 4); lo_slot = 12 + (m - 4); }
    else if (m == 8) { W = Wp1; K_off = 0;   hi_slot = 16; lo_slot = 17; }
    else             { W = Wp1; K_off = 128; hi_slot = 18; lo_slot = 19; }
    int lane = r & 63, tl = (r >> 6) & 7, ch = r >> 9;
    int kb = ch * 32 + (lane >> 4) * 8;
    int n  = tl * 16 + (lane & 15);
    unsigned short* hi = wpk + (size_t)hi_slot * 16384;
    unsigned short* lo = wpk + (size_t)lo_slot * 16384;
    for (int j = 0; j < 8; j++) {
        float w = W[(size_t)(K_off + kb + j) * 128 + n];
        unsigned short h = f2b(w);
        hi[(size_t)r * 8 + j] = h;
        lo[(size_t)r * 8 + j] = f2b(w - b2f(h));
    }
}

// ===========================================================================
// Layer 0 scatter (fp32 aggr, NODE_IN=16)
// ===========================================================================
__global__ __launch_bounds__(256) void scatter0_kernel(
    const float* __restrict__ x, const int* __restrict__ ei,
    const float* __restrict__ ea, const float* __restrict__ We0,
    const float* __restrict__ be0, float* __restrict__ aggr)
{
    int idx = blockIdx.x * 256 + threadIdx.x;
    int e = idx >> 4, c = idx & 15;
    int s = ei[e], d = ei[N_EDGES + e];
    float m = x[s * NODE_IN + c] + ea[e] * We0[c] + be0[c];
    m = fmaxf(m, 0.f);
    atomicAdd(&aggr[d * NODE_IN + c], m);
}

// ---------------------------------------------------------------------------
__device__ __forceinline__ void fma4x4(float (&acc)[4][4],
    const float4& r0, const float4& r1, const float4& r2, const float4& r3,
    const float4& w0, const float4& w1, const float4& w2, const float4& w3)
{
    float r[4][4] = {{r0.x, r0.y, r0.z, r0.w}, {r1.x, r1.y, r1.z, r1.w},
                     {r2.x, r2.y, r2.z, r2.w}, {r3.x, r3.y, r3.z, r3.w}};
    float w[4][4] = {{w0.x, w0.y, w0.z, w0.w}, {w1.x, w1.y, w1.z, w1.w},
                     {w2.x, w2.y, w2.z, w2.w}, {w3.x, w3.y, w3.z, w3.w}};
#pragma unroll
    for (int i = 0; i < 4; i++)
#pragma unroll
        for (int k = 0; k < 4; k++)
#pragma unroll
            for (int c = 0; c < 4; c++)
                acc[i][c] = fmaf(r[i][k], w[k][c], acc[i][c]);
}

// ===========================================================================
// Layer 0 MLP (fp32 vector) -> writes h as fp16
// ===========================================================================
__global__ __launch_bounds__(256) void mlp0_kernel(
    const float* __restrict__ x, const float* __restrict__ aggr,
    const float* __restrict__ W1, const float* __restrict__ b1,
    const float* __restrict__ W2, const float* __restrict__ b2,
    unsigned short* __restrict__ h)
{
    __shared__ float in0[32][20];
    __shared__ float mid[32][HID];
    const int t = threadIdx.x;
    const int q = t & 31, g = t >> 5;
    const int c0 = q * 4;
    const int base = blockIdx.x * 32;

    for (int i = t; i < 32 * NODE_IN; i += 256) {
        int r = i >> 4, cc = i & 15;
        int n = base + r;
        in0[r][cc] = x[n * NODE_IN + cc] + aggr[n * NODE_IN + cc];
    }
    __syncthreads();

    float4 bb = *(const float4*)&b1[c0];
    float acc[4][4];
#pragma unroll
    for (int i = 0; i < 4; i++) { acc[i][0] = bb.x; acc[i][1] = bb.y; acc[i][2] = bb.z; acc[i][3] = bb.w; }
    for (int k = 0; k < NODE_IN; k += 4) {
        float4 r0 = *(const float4*)&in0[g * 4 + 0][k];
        float4 r1 = *(const float4*)&in0[g * 4 + 1][k];
        float4 r2 = *(const float4*)&in0[g * 4 + 2][k];
        float4 r3 = *(const float4*)&in0[g * 4 + 3][k];
        float4 w0 = *(const float4*)&W1[(k + 0) * HID + c0];
        float4 w1 = *(const float4*)&W1[(k + 1) * HID + c0];
        float4 w2 = *(const float4*)&W1[(k + 2) * HID + c0];
        float4 w3 = *(const float4*)&W1[(k + 3) * HID + c0];
        fma4x4(acc, r0, r1, r2, r3, w0, w1, w2, w3);
    }
#pragma unroll
    for (int i = 0; i < 4; i++)
        *(float4*)&mid[g * 4 + i][c0] = make_float4(elu_f(acc[i][0]), elu_f(acc[i][1]),
                                                    elu_f(acc[i][2]), elu_f(acc[i][3]));
    __syncthreads();

    float4 bb2 = *(const float4*)&b2[c0];
    float acc2[4][4];
#pragma unroll
    for (int i = 0; i < 4; i++) { acc2[i][0] = bb2.x; acc2[i][1] = bb2.y; acc2[i][2] = bb2.z; acc2[i][3] = bb2.w; }
    for (int k = 0; k < HID; k += 4) {
        float4 r0 = *(const float4*)&mid[g * 4 + 0][k];
        float4 r1 = *(const float4*)&mid[g * 4 + 1][k];
        float4 r2 = *(const float4*)&mid[g * 4 + 2][k];
        float4 r3 = *(const float4*)&mid[g * 4 + 3][k];
        float4 w0 = *(const float4*)&W2[(k + 0) * HID + c0];
        float4 w1 = *(const float4*)&W2[(k + 1) * HID + c0];
        float4 w2 = *(const float4*)&W2[(k + 2) * HID + c0];
        float4 w3 = *(const float4*)&W2[(k + 3) * HID + c0];
        fma4x4(acc2, r0, r1, r2, r3, w0, w1, w2, w3);
    }
#pragma unroll
    for (int i = 0; i < 4; i++) {
        ushort4 o;
        o.x = f2h(elu_f(acc2[i][0])); o.y = f2h(elu_f(acc2[i][1]));
        o.z = f2h(elu_f(acc2[i][2])); o.w = f2h(elu_f(acc2[i][3]));
        *(ushort4*)&h[(size_t)(base + g * 4 + i) * HID + c0] = o;
    }
}

// ---------------------------------------------------------------------------
// A-fragment load+split from LDS (fp32 -> hi/lo bf16), layout per m120
// ---------------------------------------------------------------------------
__device__ __forceinline__ void afrag_split(const float (&buf)[16][LPAD], int lane,
                                            short8 (&ah)[4], short8 (&al)[4])
{
    const int m = lane & 15, s8 = (lane >> 4) * 8;
#pragma unroll
    for (int ch = 0; ch < 4; ch++) {
        float4 a0 = *(const float4*)&buf[m][ch * 32 + s8];
        float4 a1 = *(const float4*)&buf[m][ch * 32 + s8 + 4];
        float av[8] = {a0.x, a0.y, a0.z, a0.w, a1.x, a1.y, a1.z, a1.w};
#pragma unroll
        for (int j = 0; j < 8; j++) {
            unsigned short h = f2b(av[j]);
            ah[ch][j] = (short)h;
            al[ch][j] = (short)f2b(av[j] - b2f(h));
        }
    }
}

// ===========================================================================
// Fused GINE HID layer, v15 == R15's proven 8-slot pipeline (no spill).
// 4 waves/block x 16 sorted nodes; fp16 h storage; split-bf16 MFMA MLP.
// ===========================================================================
template <bool PRED>
__global__ __launch_bounds__(256, 4) void gine_mfma_kernel(
    const unsigned short* __restrict__ hin, const int* __restrict__ rowPtr,
    const int2* __restrict__ edgeP, const int* __restrict__ perm,
    const float* __restrict__ We, const float* __restrict__ be,
    const unsigned short* __restrict__ W1h, const unsigned short* __restrict__ W1l,
    const float* __restrict__ b1,
    const unsigned short* __restrict__ W2h, const unsigned short* __restrict__ W2l,
    const float* __restrict__ b2,
    unsigned short* __restrict__ hout,
    const unsigned short* __restrict__ P1h, const unsigned short* __restrict__ P1l,
    const unsigned short* __restrict__ P2h, const unsigned short* __restrict__ P2l,
    unsigned short* __restrict__ Pbuf)
{
    __shared__ float bufAll[4][16][LPAD];   // 35.84 KB, one slice per wave
    const int w = threadIdx.x >> 6;
    const int lane = threadIdx.x & 63;
    float (&buf)[16][LPAD] = bufAll[w];
    const int qg = lane & 15, rg = lane >> 4;
    const int c0 = qg * 8;                  // 16 lanes x 8 cols
    const int base = blockIdx.x * 64 + w * 16;

    float wev[8], bev[8];
#pragma unroll
    for (int j = 0; j < 8; j++) { wev[j] = We[c0 + j]; bev[j] = be[c0 + j]; }

    // ---- stage 1: 8-slot pipelined gather over degree-sorted nodes ----
    int nn[4], s0[4], e0[4];
    float acc[4][8];
#pragma unroll
    for (int i = 0; i < 4; i++) {
        nn[i] = perm[base + rg * 4 + i];
        s0[i] = rowPtr[nn[i]];
        e0[i] = rowPtr[nn[i] + 1];
        short8 h0 = *(const short8*)&hin[(size_t)nn[i] * HID + c0];
#pragma unroll
        for (int j = 0; j < 8; j++) acc[i][j] = h2f((unsigned short)h0[j]);
    }
    int maxd = 0;
#pragma unroll
    for (int i = 0; i < 4; i++) maxd = max(maxd, e0[i] - s0[i]);

    int idx[8]; float av[8]; bool act[8];
#pragma unroll
    for (int u = 0; u < 2; u++)
#pragma unroll
        for (int i = 0; i < 4; i++) {
            int slot = u * 4 + i;
            int j = s0[i] + u;
            act[slot] = j < e0[i];
            int jc = act[slot] ? j : (N_EDGES - 1);
            int2 ep = edgeP[jc];
            idx[slot] = ep.x;
            av[slot]  = __int_as_float(ep.y);
        }

    for (int sb = 0; sb < maxd; sb += 2) {
        short8 hraw[8];
#pragma unroll
        for (int s = 0; s < 8; s++)
            hraw[s] = *(const short8*)&hin[(size_t)idx[s] * HID + c0];

        int nidx[8]; float nav[8]; bool nact[8];
#pragma unroll
        for (int u = 0; u < 2; u++)
#pragma unroll
            for (int i = 0; i < 4; i++) {
                int slot = u * 4 + i;
                int j = s0[i] + sb + 2 + u;
                nact[slot] = j < e0[i];
                int jc = nact[slot] ? j : (N_EDGES - 1);
                int2 ep = edgeP[jc];
                nidx[slot] = ep.x;
                nav[slot]  = __int_as_float(ep.y);
            }

#pragma unroll
        for (int u = 0; u < 2; u++)
#pragma unroll
            for (int i = 0; i < 4; i++) {
                int slot = u * 4 + i;
                if (act[slot]) {
#pragma unroll
                    for (int j = 0; j < 8; j++) {
                        float hv = h2f((unsigned short)hraw[slot][j]);
                        acc[i][j] += fmaxf(fmaf(av[slot], wev[j], bev[j]) + hv, 0.f);
                    }
                }
            }
#pragma unroll
        for (int s = 0; s < 8; s++) {
            idx[s] = nidx[s]; av[s] = nav[s]; act[s] = nact[s];
        }
    }
#pragma unroll
    for (int i = 0; i < 4; i++) {
        *(float4*)&buf[rg * 4 + i][c0]     = make_float4(acc[i][0], acc[i][1], acc[i][2], acc[i][3]);
        *(float4*)&buf[rg * 4 + i][c0 + 4] = make_float4(acc[i][4], acc[i][5], acc[i][6], acc[i][7]);
    }
    __syncthreads();   // waves have equal degree (sorted) -> negligible convoy

    const int col16 = lane & 15, r0 = (lane >> 4) * 4;

    // ---- stage 2: mid = elu(in @ W1 + b1), split-bf16 MFMA, in-place ----
    {
        short8 ah[4], al[4];
        afrag_split(buf, lane, ah, al);
        float res[8][4];
#pragma unroll
        for (int tl = 0; tl < 8; tl++) {
            int col = tl * 16 + col16;
            float bv = b1[col];
            f32x4 c = {bv, bv, bv, bv};
#pragma unroll
            for (int ch = 0; ch < 4; ch++) {
                int off = ((ch * 8 + tl) * 64 + lane) * 8;
                short8 bh = *(const short8*)&W1h[off];
                short8 bl = *(const short8*)&W1l[off];
                c = __builtin_amdgcn_mfma_f32_16x16x32_bf16(ah[ch], bh, c, 0, 0, 0);
                c = __builtin_amdgcn_mfma_f32_16x16x32_bf16(al[ch], bh, c, 0, 0, 0);
                c = __builtin_amdgcn_mfma_f32_16x16x32_bf16(ah[ch], bl, c, 0, 0, 0);
            }
#pragma unroll
            for (int r = 0; r < 4; r++) res[tl][r] = elu_f(c[r]);
        }
        __syncthreads();
#pragma unroll
        for (int tl = 0; tl < 8; tl++)
#pragma unroll
            for (int r = 0; r < 4; r++)
                buf[r0 + r][tl * 16 + col16] = res[tl][r];
    }
    __syncthreads();

    // ---- stage 3: h = elu(mid @ W2 + b2), in-place ----
    {
        short8 ah[4], al[4];
        afrag_split(buf, lane, ah, al);
        float res[8][4];
#pragma unroll
        for (int tl = 0; tl < 8; tl++) {
            int col = tl * 16 + col16;
            float bv = b2[col];
            f32x4 c = {bv, bv, bv, bv};
#pragma unroll
            for (int ch = 0; ch < 4; ch++) {
                int off = ((ch * 8 + tl) * 64 + lane) * 8;
                short8 bh = *(const short8*)&W2h[off];
                short8 bl = *(const short8*)&W2l[off];
                c = __builtin_amdgcn_mfma_f32_16x16x32_bf16(ah[ch], bh, c, 0, 0, 0);
                c = __builtin_amdgcn_mfma_f32_16x16x32_bf16(al[ch], bh, c, 0, 0, 0);
                c = __builtin_amdgcn_mfma_f32_16x16x32_bf16(ah[ch], bl, c, 0, 0, 0);
            }
#pragma unroll
            for (int r = 0; r < 4; r++) res[tl][r] = elu_f(c[r]);
        }
        __syncthreads();
#pragma unroll
        for (int tl = 0; tl < 8; tl++)
#pragma unroll
            for (int r = 0; r < 4; r++)
                buf[r0 + r][tl * 16 + col16] = res[tl][r];
    }
    __syncthreads();

    if constexpr (!PRED) {
        // fp16 store of h (row-scattered by perm; 256 B contiguous per row)
#pragma unroll
        for (int i = 0; i < 4; i++) {
            short8 o;
#pragma unroll
            for (int j = 0; j < 8; j++) o[j] = (short)f2h(buf[rg * 4 + i][c0 + j]);
            *(short8*)&hout[(size_t)nn[i] * HID + c0] = o;
        }
    } else {
        // P1|P2 = h @ Wp1 halves, emit bf16 packed rows (perm-indexed)
        short8 ah[4], al[4];
        afrag_split(buf, lane, ah, al);
        int pn[4];
#pragma unroll
        for (int r = 0; r < 4; r++) pn[r] = perm[base + r0 + r];
#pragma unroll
        for (int tl = 0; tl < 8; tl++) {
            int col = tl * 16 + col16;
            f32x4 c1 = {0.f, 0.f, 0.f, 0.f};
            f32x4 c2 = {0.f, 0.f, 0.f, 0.f};
#pragma unroll
            for (int ch = 0; ch < 4; ch++) {
                int off = ((ch * 8 + tl) * 64 + lane) * 8;
                short8 bh1 = *(const short8*)&P1h[off];
                short8 bl1 = *(const short8*)&P1l[off];
                c1 = __builtin_amdgcn_mfma_f32_16x16x32_bf16(ah[ch], bh1, c1, 0, 0, 0);
                c1 = __builtin_amdgcn_mfma_f32_16x16x32_bf16(al[ch], bh1, c1, 0, 0, 0);
                c1 = __builtin_amdgcn_mfma_f32_16x16x32_bf16(ah[ch], bl1, c1, 0, 0, 0);
                short8 bh2 = *(const short8*)&P2h[off];
                short8 bl2 = *(const short8*)&P2l[off];
                c2 = __builtin_amdgcn_mfma_f32_16x16x32_bf16(ah[ch], bh2, c2, 0, 0, 0);
                c2 = __builtin_amdgcn_mfma_f32_16x16x32_bf16(al[ch], bh2, c2, 0, 0, 0);
                c2 = __builtin_amdgcn_mfma_f32_16x16x32_bf16(ah[ch], bl2, c2, 0, 0, 0);
            }
#pragma unroll
            for (int r = 0; r < 4; r++) {
                size_t n = (size_t)pn[r];
                Pbuf[n * 256 + col]       = f2b(c1[r]);
                Pbuf[n * 256 + 128 + col] = f2b(c2[r]);
            }
        }
    }
}

// ===========================================================================
// Edge predictor tail, v2: NODE-PARALLEL over dst (CSR), P2[dst] loaded once
// per node, P1[src] gathered per edge, out scattered by orig edge id.
// 32 lanes per node, 8 nodes per block, degree-balanced via perm.
// ===========================================================================
__global__ __launch_bounds__(256) void pred_node_kernel(
    const unsigned short* __restrict__ Pbuf, const int* __restrict__ rowPtr,
    const int2* __restrict__ edgeP, const int* __restrict__ eorig,
    const int* __restrict__ perm,
    const float* __restrict__ bp1, const float* __restrict__ Wp2,
    const float* __restrict__ bp2, float* __restrict__ out)
{
    const int t = threadIdx.x;
    const int lane = t & 31, grp = t >> 5;
    const int n = perm[blockIdx.x * 8 + grp];    // 12500 blocks exactly
    const int c0 = lane * 4;

    ushort4 ub = *(const ushort4*)&Pbuf[(size_t)n * 256 + 128 + c0];
    float4 bb = *(const float4*)&bp1[c0];
    float4 wv = *(const float4*)&Wp2[c0];
    float p2b0 = b2f(ub.x) + bb.x, p2b1 = b2f(ub.y) + bb.y;
    float p2b2 = b2f(ub.z) + bb.z, p2b3 = b2f(ub.w) + bb.w;
    float bias2 = bp2[0];

    int s0 = rowPtr[n], e1 = rowPtr[n + 1];
    for (int j = s0; j < e1; j++) {
        int src = edgeP[j].x;
        int oe = eorig[j];
        ushort4 ua = *(const ushort4*)&Pbuf[(size_t)src * 256 + c0];
        float r = elu_f(b2f(ua.x) + p2b0) * wv.x
                + elu_f(b2f(ua.y) + p2b1) * wv.y
                + elu_f(b2f(ua.z) + p2b2) * wv.z
                + elu_f(b2f(ua.w) + p2b3) * wv.w;
#pragma unroll
        for (int off = 16; off > 0; off >>= 1) r += __shfl_down(r, off, 32);
        if (lane == 0) out[oe] = r + bias2;
    }
}

// ===========================================================================
extern "C" void kernel_launch(void* const* d_in, const int* in_sizes, int n_in,
                              void* d_out, int out_size, void* d_ws, size_t ws_size,
                              hipStream_t stream) {
    const float* x    = (const float*)d_in[0];
    const int*   ei   = (const int*)d_in[1];
    const float* ea   = (const float*)d_in[2];
    const float* We0  = (const float*)d_in[3];
    const float* be0  = (const float*)d_in[4];
    const float* W10  = (const float*)d_in[5];
    const float* b10  = (const float*)d_in[6];
    const float* W20  = (const float*)d_in[7];
    const float* b20  = (const float*)d_in[8];
    const float* We_s = (const float*)d_in[9];
    const float* be_s = (const float*)d_in[10];
    const float* W1_s = (const float*)d_in[11];
    const float* b1_s = (const float*)d_in[12];
    const float* W2_s = (const float*)d_in[13];
    const float* b2_s = (const float*)d_in[14];
    const float* Wp1  = (const float*)d_in[15];
    const float* bp1  = (const float*)d_in[16];
    const float* Wp2  = (const float*)d_in[17];
    const float* bp2  = (const float*)d_in[18];
    float* out = (float*)d_out;

    // workspace: h16A (25.6MB) | h16B (25.6MB) | Pbuf (51.2MB) | R
    unsigned short* h16A = (unsigned short*)d_ws;
    unsigned short* h16B = h16A + (size_t)N_NODES * HID;
    unsigned short* Pbuf = h16B + (size_t)N_NODES * HID;
    float* R = (float*)(Pbuf + (size_t)N_NODES * 256);

    float* aggr0 = R;                                  // N*16 f32
    int* deg     = (int*)(aggr0 + (size_t)N_NODES * NODE_IN);
    int* rowPtr  = deg + N_NODES;                      // N+1 ints
    int* cursor  = rowPtr + N_NODES + 1;
    int2* edgeP  = (int2*)(cursor + N_NODES);          // 500k int2
    int* eorig   = (int*)(edgeP + N_EDGES);            // 500k ints
    int* bsum    = eorig + N_EDGES;
    int* boff    = bsum + NB_SCAN;
    int* perm    = boff + NB_SCAN;                     // PERM_PAD ints
    int* blockHist = perm + PERM_PAD;                  // 98*1024
    int* binTot   = blockHist + NB_SCAN * DBINS;       // 1024
    int* binStart = binTot + DBINS;                    // 1024

    // packed weights: 20 slots x 16384 ushorts = 640 KB, at R+24MB
    unsigned short* wpk = (unsigned short*)(R + (size_t)6 * 1024 * 1024);

    // ----- CSR build -----
    hipMemsetAsync(deg, 0, N_NODES * sizeof(int), stream);
    deg_count_kernel<<<(N_EDGES + 255) / 256, 256, 0, stream>>>(ei, deg);
    scanA_kernel<<<NB_SCAN, SCAN_CHUNK, 0, stream>>>(deg, bsum);
    scanB_kernel<<<1, 64, 0, stream>>>(bsum, boff, rowPtr);
    scanC_kernel<<<NB_SCAN, SCAN_CHUNK, 0, stream>>>(deg, boff, rowPtr, cursor);
    fill_kernel<<<(N_EDGES + 255) / 256, 256, 0, stream>>>(ei, ea, cursor, edgeP, eorig);

    // ----- degree counting sort (contention-free, parallel scan) -> perm -----
    hipMemsetAsync(perm, 0, PERM_PAD * sizeof(int), stream);   // pad tail -> node 0
    s1_blockhist_kernel<<<NB_SCAN, DBINS, 0, stream>>>(deg, blockHist);
    s2a_colscan_kernel<<<4, 256, 0, stream>>>(blockHist, binTot);
    s2b_binscan_kernel<<<1, DBINS, 0, stream>>>(binTot, binStart);
    s3_scatter_kernel<<<NB_SCAN, DBINS, 0, stream>>>(deg, blockHist, binStart, perm);

    // ----- weight packing (single dispatch) -----
    pack_all_kernel<<<80, 256, 0, stream>>>(W1_s, W2_s, Wp1, wpk);

    // ----- layer 0 (NODE_IN -> HID) -----
    hipMemsetAsync(aggr0, 0, (size_t)N_NODES * NODE_IN * sizeof(float), stream);
    scatter0_kernel<<<(N_EDGES * NODE_IN) / 256, 256, 0, stream>>>(x, ei, ea, We0, be0, aggr0);
    mlp0_kernel<<<N_NODES / 32, 256, 0, stream>>>(x, aggr0, W10, b10, W20, b20, h16A);

    // ----- layers 1..3 (HID -> HID), ping-pong -----
    const size_t WSLOT = 16384;
    unsigned short* hin = h16A; unsigned short* hout_ = h16B;
    for (int l = 0; l < 3; l++) {
        gine_mfma_kernel<false><<<NBLK64, 256, 0, stream>>>(
            hin, rowPtr, edgeP, perm,
            We_s + l * HID, be_s + l * HID,
            wpk + (0 + l) * WSLOT, wpk + (4 + l) * WSLOT, b1_s + l * HID,
            wpk + (8 + l) * WSLOT, wpk + (12 + l) * WSLOT, b2_s + l * HID,
            hout_, nullptr, nullptr, nullptr, nullptr, nullptr);
        unsigned short* tmp = hin; hin = hout_; hout_ = tmp;
    }
    // hin == h16B after 3 swaps

    // ----- layer 4 fused with pred GEMM -----
    {
        const int l = 3;
        gine_mfma_kernel<true><<<NBLK64, 256, 0, stream>>>(
            hin, rowPtr, edgeP, perm,
            We_s + l * HID, be_s + l * HID,
            wpk + (0 + l) * WSLOT, wpk + (4 + l) * WSLOT, b1_s + l * HID,
            wpk + (8 + l) * WSLOT, wpk + (12 + l) * WSLOT, b2_s + l * HID,
            nullptr, wpk + 16 * WSLOT, wpk + 17 * WSLOT,
            wpk + 18 * WSLOT, wpk + 19 * WSLOT, Pbuf);
    }

    // ----- edge predictor tail (node-parallel, CSR-grouped) -----
    pred_node_kernel<<<N_NODES / 8, 256, 0, stream>>>(
        Pbuf, rowPtr, edgeP, eorig, perm, bp1, Wp2, bp2, out);
}